// Round 10
// baseline (56.528 us; speedup 1.0000x reference)
//
#include <hip/hip_runtime.h>

#define BATCH 128
#define DIM 256
#define NTH 6
#define NF 1536          // NUM_FACTS
#define NODES 1023
#define NPAD 1024
#define OD 8
#define INV_TAU (1.0f/0.7f)
#define CLIP_EPS 1e-6f

// GEMM tiling (round-7 baseline config; 1x total extrapolates to 20.9us)
#define BN 16            // nodes per tile
#define NTILES 64        // 64 * 16 = 1024 >= 1023
#define KC 192           // k per chunk
#define KSPLIT 8         // 8 * 192 = 1536
#define GP 200           // LDS g pitch in halves

typedef _Float16 half_t;
typedef __attribute__((ext_vector_type(8))) _Float16 half8;
typedef __attribute__((ext_vector_type(4))) float f32x4;

// ws layout (bytes)
#define OFF_PART 0                         // partial [8][128][1024] f32 = 4 MiB
#define OFF_CS   (4*1024*1024)             // cS [8][2][1024] f32 = 64 KiB
#define OFF_FT   (4*1024*1024 + 65536)     // fT [192][128][8] f16 = 384 KiB

__global__ __launch_bounds__(256) void k_facts(const float* __restrict__ x,
                                               const float* __restrict__ th,
                                               const float* __restrict__ sl,
                                               half_t* __restrict__ fT) {
    const int idx = blockIdx.x * 256 + threadIdx.x;   // (k8*128 + b), 24576 total
    const int b = idx & 127;
    const int k8 = idx >> 7;                          // 0..191
    const int kbase = k8 * 8;
    const int d0 = kbase / NTH;
    const int jsw = NTH - (kbase - NTH * d0);
    const float x0 = x[b * DIM + d0];
    const float x1 = x[b * DIM + d0 + 1];
    float4 tA = *(const float4*)&th[kbase];
    float4 tB = *(const float4*)&th[kbase + 4];
    float4 sA = *(const float4*)&sl[kbase];
    float4 sB = *(const float4*)&sl[kbase + 4];
    float t8[8] = {tA.x, tA.y, tA.z, tA.w, tB.x, tB.y, tB.z, tB.w};
    float s8[8] = {sA.x, sA.y, sA.z, sA.w, sB.x, sB.y, sB.z, sB.w};
    union { half_t h[8]; uint4 u; } p;
    #pragma unroll
    for (int j = 0; j < 8; ++j) {
        float xv = (j < jsw) ? x0 : x1;
        float z = (xv - t8[j]) * s8[j];
        p.h[j] = (half_t)(1.0f / (1.0f + __expf(-z)));
    }
    *(uint4*)&fT[(size_t)idx * 8] = p.u;
}

__global__ __launch_bounds__(256) void k_gemm(const float* __restrict__ logits,
                                              const half_t* __restrict__ fT,
                                              float* __restrict__ partial,
                                              float* __restrict__ cS) {
    __shared__ __align__(16) half_t gs[BN * GP];
    const int tid = threadIdx.x;
    const int tile = blockIdx.x >> 3;       // 0..63
    const int chunk = blockIdx.x & 7;       // 0..7
    const int n0 = tile * BN;
    const int k0 = chunk * KC;

    // prefetch B fragments (fT, coalesced 256B segments) into registers
    const int wave = tid >> 6;
    const int lane = tid & 63;
    const int bcol = lane & 15;
    const int kq = lane >> 4;               // 0..3
    const int b0 = wave * 32;
    const half8* fp = (const half8*)(fT + ((size_t)((k0 >> 3) + kq) * BATCH + b0 + bcol) * 8);
    half8 bva[6], bvb[6];
    #pragma unroll
    for (int s = 0; s < 6; ++s) {
        bva[s] = fp[(size_t)s * 512];
        bvb[s] = fp[(size_t)s * 512 + 16];
    }

    // stage g = e1 - e2 (fp16) into LDS; per-chunk c = sum e2, S = sum(e1+e2)
    const int r = tid >> 4;                 // 0..15 node row
    const int j = tid & 15;                 // 0..15 lane in row
    const int n = n0 + r;
    float cpart = 0.f, spart = 0.f;
    if (n < NODES) {
        const float* row = logits + (size_t)n * (2 * NF) + k0;
        #pragma unroll
        for (int i = 0; i < 6; ++i) {
            int kp = j * 2 + 32 * i;
            float2 a1 = *(const float2*)&row[kp];
            float2 a2 = *(const float2*)&row[kp + NF];
            float e10 = __expf(a1.x * INV_TAU), e11 = __expf(a1.y * INV_TAU);
            float e20 = __expf(a2.x * INV_TAU), e21 = __expf(a2.y * INV_TAU);
            union { half_t h[2]; unsigned int u; } p;
            p.h[0] = (half_t)(e10 - e20); p.h[1] = (half_t)(e11 - e21);
            *(unsigned int*)&gs[r * GP + kp] = p.u;
            cpart += e20 + e21;
            spart += e10 + e11 + e20 + e21;
        }
    } else {
        #pragma unroll
        for (int i = 0; i < 6; ++i)
            *(unsigned int*)&gs[r * GP + j * 2 + 32 * i] = 0u;
    }
    cpart += __shfl_xor(cpart, 1); cpart += __shfl_xor(cpart, 2);
    cpart += __shfl_xor(cpart, 4); cpart += __shfl_xor(cpart, 8);
    spart += __shfl_xor(spart, 1); spart += __shfl_xor(spart, 2);
    spart += __shfl_xor(spart, 4); spart += __shfl_xor(spart, 8);
    if (j == 0 && n < NODES) {
        cS[(size_t)chunk * (2 * NPAD) + n] = cpart;
        cS[(size_t)chunk * (2 * NPAD) + NPAD + n] = spart;
    }
    __syncthreads();

    // MFMA: out[n 16][b 128]; 4 waves x 2 b-tiles of 16
    f32x4 acc0 = {0.f, 0.f, 0.f, 0.f};
    f32x4 acc1 = {0.f, 0.f, 0.f, 0.f};
    const half_t* ga = gs + bcol * GP + kq * 8;
    #pragma unroll
    for (int s = 0; s < 6; ++s) {
        half8 av = *(const half8*)(ga + s * 32);
        acc0 = __builtin_amdgcn_mfma_f32_16x16x32_f16(av, bva[s], acc0, 0, 0, 0);
        acc1 = __builtin_amdgcn_mfma_f32_16x16x32_f16(av, bvb[s], acc1, 0, 0, 0);
    }

    float* p0 = partial + (size_t)chunk * (BATCH * NPAD) + (size_t)(b0 + bcol) * NPAD + n0 + kq * 4;
    *(f32x4*)p0 = acc0;
    *(f32x4*)(p0 + (size_t)16 * NPAD) = acc1;
}

__global__ __launch_bounds__(256) void k_tree(const float* __restrict__ partial,
                                              const float* __restrict__ cS,
                                              const float* __restrict__ LV,
                                              float* __restrict__ out) {
    __shared__ float tl[NPAD];
    __shared__ float Abuf[512 * OD];
    __shared__ float Bbuf[256 * OD];
    const int b = blockIdx.x;
    const int tid = threadIdx.x;

    {
        const int n4 = tid * 4;
        float4 s = make_float4(0.f, 0.f, 0.f, 0.f);
        float4 c = make_float4(0.f, 0.f, 0.f, 0.f);
        float4 S = make_float4(0.f, 0.f, 0.f, 0.f);
        #pragma unroll
        for (int ch = 0; ch < KSPLIT; ++ch) {
            float4 p = *(const float4*)&partial[(size_t)ch * (BATCH * NPAD) + (size_t)b * NPAD + n4];
            float4 cc = *(const float4*)&cS[(size_t)ch * (2 * NPAD) + n4];
            float4 SS = *(const float4*)&cS[(size_t)ch * (2 * NPAD) + NPAD + n4];
            s.x += p.x; s.y += p.y; s.z += p.z; s.w += p.w;
            c.x += cc.x; c.y += cc.y; c.z += cc.z; c.w += cc.w;
            S.x += SS.x; S.y += SS.y; S.z += SS.z; S.w += SS.w;
        }
        float4 tv;
        tv.x = fminf(fmaxf((s.x + c.x) / S.x, CLIP_EPS), 1.0f - CLIP_EPS);
        tv.y = fminf(fmaxf((s.y + c.y) / S.y, CLIP_EPS), 1.0f - CLIP_EPS);
        tv.z = fminf(fmaxf((s.z + c.z) / S.z, CLIP_EPS), 1.0f - CLIP_EPS);
        tv.w = fminf(fmaxf((s.w + c.w) / S.w, CLIP_EPS), 1.0f - CLIP_EPS);
        *(float4*)&tl[n4] = tv;
    }
    __syncthreads();

    for (int w = tid; w < 512 * OD; w += 256) {
        int i = w >> 3, o = w & 7;
        float tv = tl[511 + i];
        Abuf[w] = (1.0f - tv) * LV[i * 16 + o] + tv * LV[i * 16 + 8 + o];
    }
    __syncthreads();

    float* cur = Abuf;
    float* nxt = Bbuf;
    for (int lev = 8; lev >= 0; --lev) {
        int cnt = 1 << lev;
        int base = cnt - 1;
        for (int w = tid; w < cnt * OD; w += 256) {
            int i = w >> 3, o = w & 7;
            float tv = tl[base + i];
            nxt[w] = (1.0f - tv) * cur[i * 16 + o] + tv * cur[i * 16 + 8 + o];
        }
        __syncthreads();
        float* tmp = cur; cur = nxt; nxt = tmp;
    }
    if (tid < OD) out[b * OD + tid] = cur[tid];
}

extern "C" void kernel_launch(void* const* d_in, const int* in_sizes, int n_in,
                              void* d_out, int out_size, void* d_ws, size_t ws_size,
                              hipStream_t stream) {
    const float* x      = (const float*)d_in[0];
    const float* th     = (const float*)d_in[1];
    const float* sl     = (const float*)d_in[2];
    const float* logits = (const float*)d_in[3];
    const float* LV     = (const float*)d_in[4];
    float* out = (float*)d_out;
    char* ws = (char*)d_ws;
    float* partial = (float*)(ws + OFF_PART);
    float* cS      = (float*)(ws + OFF_CS);
    half_t* fT     = (half_t*)(ws + OFF_FT);

    k_facts<<<96, 256, 0, stream>>>(x, th, sl, fT);
    k_gemm<<<NTILES * KSPLIT, 256, 0, stream>>>(logits, fT, partial, cS);
    // CALIBRATION: k_tree is idempotent (reads partial/cS/LV, writes same out).
    // total = 20.9 + 9*T_tree'  ->  splits the 17.1us residual.
    for (int rep = 0; rep < 10; ++rep)
        k_tree<<<BATCH, 256, 0, stream>>>(partial, cS, LV, out);
}

// Round 11
// 18.198 us; speedup vs baseline: 3.1063x; 3.1063x over previous
//
#include <hip/hip_runtime.h>

#define BATCH 128
#define DIM 256
#define NTH 6
#define NF 1536          // NUM_FACTS
#define NODES 1023
#define NPAD 1024
#define OD 8
#define INV_TAU (1.0f/0.7f)
#define CLIP_EPS 1e-6f

// GEMM tiling (round-4 anchor config)
#define BN 16            // nodes per tile
#define NTILES 64        // 64 * 16 = 1024 >= 1023
#define KC 192           // k per chunk
#define KSPLIT 8         // 8 * 192 = 1536
#define GP 200           // LDS g pitch in halves

typedef _Float16 half_t;
typedef __attribute__((ext_vector_type(8))) _Float16 half8;
typedef __attribute__((ext_vector_type(4))) _Float16 half4;
typedef __attribute__((ext_vector_type(4))) float f32x4;

// ws layout (bytes)
#define OFF_PART 0                         // partial [8][128][1024] f16 = 2 MiB
#define OFF_CS   (2*1024*1024)             // cS [8][2][1024] f32 = 64 KiB
#define OFF_FT   (2*1024*1024 + 65536)     // fT [192][128][8] f16 = 384 KiB

__global__ __launch_bounds__(256) void k_facts(const float* __restrict__ x,
                                               const float* __restrict__ th,
                                               const float* __restrict__ sl,
                                               half_t* __restrict__ fT) {
    const int idx = blockIdx.x * 256 + threadIdx.x;   // (k8*128 + b), 24576 total
    const int b = idx & 127;
    const int k8 = idx >> 7;                          // 0..191
    const int kbase = k8 * 8;
    const int d0 = kbase / NTH;
    const int jsw = NTH - (kbase - NTH * d0);
    const float x0 = x[b * DIM + d0];
    const float x1 = x[b * DIM + d0 + 1];
    float4 tA = *(const float4*)&th[kbase];
    float4 tB = *(const float4*)&th[kbase + 4];
    float4 sA = *(const float4*)&sl[kbase];
    float4 sB = *(const float4*)&sl[kbase + 4];
    float t8[8] = {tA.x, tA.y, tA.z, tA.w, tB.x, tB.y, tB.z, tB.w};
    float s8[8] = {sA.x, sA.y, sA.z, sA.w, sB.x, sB.y, sB.z, sB.w};
    union { half_t h[8]; uint4 u; } p;
    #pragma unroll
    for (int j = 0; j < 8; ++j) {
        float xv = (j < jsw) ? x0 : x1;
        float z = (xv - t8[j]) * s8[j];
        p.h[j] = (half_t)(1.0f / (1.0f + __expf(-z)));
    }
    *(uint4*)&fT[(size_t)idx * 8] = p.u;
}

__global__ __launch_bounds__(256) void k_gemm(const float* __restrict__ logits,
                                              const half_t* __restrict__ fT,
                                              half_t* __restrict__ partial,
                                              float* __restrict__ cS) {
    __shared__ __align__(16) half_t gs[BN * GP];
    const int tid = threadIdx.x;
    const int tile = blockIdx.x >> 3;       // 0..63
    const int chunk = blockIdx.x & 7;       // 0..7
    const int n0 = tile * BN;
    const int k0 = chunk * KC;

    // prefetch B fragments (fT, coalesced 256B segments) into registers
    const int wave = tid >> 6;
    const int lane = tid & 63;
    const int bcol = lane & 15;
    const int kq = lane >> 4;               // 0..3
    const int b0 = wave * 32;
    const half8* fp = (const half8*)(fT + ((size_t)((k0 >> 3) + kq) * BATCH + b0 + bcol) * 8);
    half8 bva[6], bvb[6];
    #pragma unroll
    for (int s = 0; s < 6; ++s) {
        bva[s] = fp[(size_t)s * 512];
        bvb[s] = fp[(size_t)s * 512 + 16];
    }

    // stage g = e1 - e2 (fp16) into LDS; per-chunk c = sum e2, S = sum(e1+e2)
    const int r = tid >> 4;                 // 0..15 node row
    const int j = tid & 15;                 // 0..15 lane in row
    const int n = n0 + r;
    float cpart = 0.f, spart = 0.f;
    if (n < NODES) {
        const float* row = logits + (size_t)n * (2 * NF) + k0;
        #pragma unroll
        for (int i = 0; i < 6; ++i) {
            int kp = j * 2 + 32 * i;
            float2 a1 = *(const float2*)&row[kp];
            float2 a2 = *(const float2*)&row[kp + NF];
            float e10 = __expf(a1.x * INV_TAU), e11 = __expf(a1.y * INV_TAU);
            float e20 = __expf(a2.x * INV_TAU), e21 = __expf(a2.y * INV_TAU);
            union { half_t h[2]; unsigned int u; } p;
            p.h[0] = (half_t)(e10 - e20); p.h[1] = (half_t)(e11 - e21);
            *(unsigned int*)&gs[r * GP + kp] = p.u;
            cpart += e20 + e21;
            spart += e10 + e11 + e20 + e21;
        }
    } else {
        #pragma unroll
        for (int i = 0; i < 6; ++i)
            *(unsigned int*)&gs[r * GP + j * 2 + 32 * i] = 0u;
    }
    cpart += __shfl_xor(cpart, 1); cpart += __shfl_xor(cpart, 2);
    cpart += __shfl_xor(cpart, 4); cpart += __shfl_xor(cpart, 8);
    spart += __shfl_xor(spart, 1); spart += __shfl_xor(spart, 2);
    spart += __shfl_xor(spart, 4); spart += __shfl_xor(spart, 8);
    if (j == 0 && n < NODES) {
        cS[(size_t)chunk * (2 * NPAD) + n] = cpart;
        cS[(size_t)chunk * (2 * NPAD) + NPAD + n] = spart;
    }
    __syncthreads();

    // MFMA: out[n 16][b 128]; 4 waves x 2 b-tiles of 16
    f32x4 acc0 = {0.f, 0.f, 0.f, 0.f};
    f32x4 acc1 = {0.f, 0.f, 0.f, 0.f};
    const half_t* ga = gs + bcol * GP + kq * 8;
    #pragma unroll
    for (int s = 0; s < 6; ++s) {
        half8 av = *(const half8*)(ga + s * 32);
        acc0 = __builtin_amdgcn_mfma_f32_16x16x32_f16(av, bva[s], acc0, 0, 0, 0);
        acc1 = __builtin_amdgcn_mfma_f32_16x16x32_f16(av, bvb[s], acc1, 0, 0, 0);
    }

    // D layout: col(b)=lane&15, row(n)=(lane>>4)*4+reg ; fp16 partial stores
    half4 h0, h1;
    #pragma unroll
    for (int i = 0; i < 4; ++i) { h0[i] = (half_t)acc0[i]; h1[i] = (half_t)acc1[i]; }
    half_t* p0 = partial + (size_t)chunk * (BATCH * NPAD) + (size_t)(b0 + bcol) * NPAD + n0 + kq * 4;
    *(half4*)p0 = h0;
    *(half4*)(p0 + (size_t)16 * NPAD) = h1;
}

// leaf-centric tree: 1 block per batch, 4 leaves per thread, 1 syncthreads
__global__ __launch_bounds__(256) void k_tree(const half_t* __restrict__ partial,
                                              const float* __restrict__ cS,
                                              const float* __restrict__ LV,
                                              float* __restrict__ out) {
    __shared__ float tl[NPAD];
    __shared__ float red[4][OD];
    const int b = blockIdx.x;
    const int tid = threadIdx.x;

    // t for 4 nodes per thread (split-K reduce, fp16 partials)
    {
        const int n4 = tid * 4;
        float s0 = 0.f, s1 = 0.f, s2 = 0.f, s3 = 0.f;
        float c0 = 0.f, c1 = 0.f, c2 = 0.f, c3 = 0.f;
        float S0 = 0.f, S1 = 0.f, S2 = 0.f, S3 = 0.f;
        #pragma unroll
        for (int ch = 0; ch < KSPLIT; ++ch) {
            half4 p = *(const half4*)&partial[(size_t)ch * (BATCH * NPAD) + (size_t)b * NPAD + n4];
            float4 cc = *(const float4*)&cS[(size_t)ch * (2 * NPAD) + n4];
            float4 SS = *(const float4*)&cS[(size_t)ch * (2 * NPAD) + NPAD + n4];
            s0 += (float)p[0]; s1 += (float)p[1]; s2 += (float)p[2]; s3 += (float)p[3];
            c0 += cc.x; c1 += cc.y; c2 += cc.z; c3 += cc.w;
            S0 += SS.x; S1 += SS.y; S2 += SS.z; S3 += SS.w;
        }
        tl[n4 + 0] = fminf(fmaxf((s0 + c0) / S0, CLIP_EPS), 1.0f - CLIP_EPS);
        tl[n4 + 1] = fminf(fmaxf((s1 + c1) / S1, CLIP_EPS), 1.0f - CLIP_EPS);
        tl[n4 + 2] = fminf(fmaxf((s2 + c2) / S2, CLIP_EPS), 1.0f - CLIP_EPS);
        tl[n4 + 3] = fminf(fmaxf((s3 + c3) / S3, CLIP_EPS), 1.0f - CLIP_EPS);
    }
    __syncthreads();

    // each thread: 4 leaves, path product over 10 levels, FMA with leaf_value
    float acc[OD] = {0.f, 0.f, 0.f, 0.f, 0.f, 0.f, 0.f, 0.f};
    #pragma unroll
    for (int q = 0; q < 4; ++q) {
        const int l = tid * 4 + q;
        float p = 1.0f;
        #pragma unroll
        for (int d = 0; d < 10; ++d) {
            const int node = (1 << d) - 1 + (l >> (10 - d));
            const float tv = tl[node];
            p *= ((l >> (9 - d)) & 1) ? tv : (1.0f - tv);
        }
        const float4* lv = (const float4*)&LV[l * OD];
        float4 lo = lv[0], hi = lv[1];
        acc[0] += p * lo.x; acc[1] += p * lo.y; acc[2] += p * lo.z; acc[3] += p * lo.w;
        acc[4] += p * hi.x; acc[5] += p * hi.y; acc[6] += p * hi.z; acc[7] += p * hi.w;
    }

    // butterfly reduce over the 64-lane wave
    #pragma unroll
    for (int off = 1; off < 64; off <<= 1) {
        #pragma unroll
        for (int o = 0; o < OD; ++o)
            acc[o] += __shfl_xor(acc[o], off);
    }
    const int wv = tid >> 6;
    if ((tid & 63) == 0) {
        #pragma unroll
        for (int o = 0; o < OD; ++o) red[wv][o] = acc[o];
    }
    __syncthreads();
    if (tid < OD)
        out[b * OD + tid] = red[0][tid] + red[1][tid] + red[2][tid] + red[3][tid];
}

extern "C" void kernel_launch(void* const* d_in, const int* in_sizes, int n_in,
                              void* d_out, int out_size, void* d_ws, size_t ws_size,
                              hipStream_t stream) {
    const float* x      = (const float*)d_in[0];
    const float* th     = (const float*)d_in[1];
    const float* sl     = (const float*)d_in[2];
    const float* logits = (const float*)d_in[3];
    const float* LV     = (const float*)d_in[4];
    float* out = (float*)d_out;
    char* ws = (char*)d_ws;
    half_t* partial = (half_t*)(ws + OFF_PART);
    float* cS       = (float*)(ws + OFF_CS);
    half_t* fT      = (half_t*)(ws + OFF_FT);

    k_facts<<<96, 256, 0, stream>>>(x, th, sl, fT);
    k_gemm<<<NTILES * KSPLIT, 256, 0, stream>>>(logits, fT, partial, cS);
    k_tree<<<BATCH, 256, 0, stream>>>(partial, cS, LV, out);
}